// Round 3
// baseline (394.379 us; speedup 1.0000x reference)
//
#include <hip/hip_runtime.h>
#include <hip/hip_bf16.h>
#include <stdint.h>

#define DM   1024
#define NH   16
#define DH   64
#define TSEQ 2048
#define BATCH 4
#define NROW 8192      // B*T
#define NQKV 3072

typedef __attribute__((ext_vector_type(8))) __bf16 bf16x8;
typedef __attribute__((ext_vector_type(4))) float  f32x4;

static __device__ __forceinline__ void gload_lds16(const __bf16* g, __bf16* l) {
  __builtin_amdgcn_global_load_lds((const __attribute__((address_space(1))) void*)g,
                                   (__attribute__((address_space(3))) void*)l, 16, 0, 0);
}

// ---------------- fp32 -> bf16 convert, 8 elems/thread ----------------
__global__ __launch_bounds__(256) void cvt_bf16(const float* __restrict__ in,
                                                __bf16* __restrict__ out, int n8) {
  int i = blockIdx.x * blockDim.x + threadIdx.x;
  int stride = gridDim.x * blockDim.x;
  for (; i < n8; i += stride) {
    const float4* p = (const float4*)(in + (size_t)i * 8);
    float4 a = p[0], b = p[1];
    bf16x8 o;
    o[0] = (__bf16)a.x; o[1] = (__bf16)a.y; o[2] = (__bf16)a.z; o[3] = (__bf16)a.w;
    o[4] = (__bf16)b.x; o[5] = (__bf16)b.y; o[6] = (__bf16)b.z; o[7] = (__bf16)b.w;
    *(bf16x8*)(out + (size_t)i * 8) = o;
  }
}

// ---------------- bf16 GEMM, C = A[M,K] * B[N,K]^T (m97 structure) ----------------
// 128x128 tile, BK=64, 4 waves (2x2 of 64x64), global_load_lds width 16, linear LDS.
template <int OUTF32>
__global__ __launch_bounds__(256) void gemm_bt(const __bf16* __restrict__ A,
                                               const __bf16* __restrict__ B,
                                               void* __restrict__ C,
                                               int M, int N, int K) {
  __shared__ __bf16 As[128 * 64];
  __shared__ __bf16 Bs[128 * 64];
  const int nbn = N >> 7;
  const int bm = blockIdx.x / nbn, bn = blockIdx.x % nbn;
  const int tid = threadIdx.x;
  const int lane = tid & 63, wid = tid >> 6;
  const int wr = wid >> 1, wc = wid & 1;

  f32x4 acc[4][4];
#pragma unroll
  for (int i = 0; i < 4; i++)
#pragma unroll
    for (int j = 0; j < 4; j++) acc[i][j] = (f32x4){0.f, 0.f, 0.f, 0.f};

  const __bf16* Abase = A + (size_t)(bm * 128) * K;
  const __bf16* Bbase = B + (size_t)(bn * 128) * K;

  for (int k0 = 0; k0 < K; k0 += 64) {
    __syncthreads();
#pragma unroll
    for (int it = 0; it < 4; ++it) {
      int e = it * 256 + tid;
      int row = e >> 3, c = (e & 7) * 8;
      gload_lds16(Abase + (size_t)row * K + k0 + c, As + e * 8);
      gload_lds16(Bbase + (size_t)row * K + k0 + c, Bs + e * 8);
    }
    __syncthreads();
#pragma unroll
    for (int kk = 0; kk < 2; ++kk) {
      const int kb = kk * 32 + (lane >> 4) * 8;
      bf16x8 af[4], bfr[4];
#pragma unroll
      for (int i = 0; i < 4; i++)
        af[i] = *(const bf16x8*)&As[(wr * 64 + i * 16 + (lane & 15)) * 64 + kb];
#pragma unroll
      for (int j = 0; j < 4; j++)
        bfr[j] = *(const bf16x8*)&Bs[(wc * 64 + j * 16 + (lane & 15)) * 64 + kb];
#pragma unroll
      for (int i = 0; i < 4; i++)
#pragma unroll
        for (int j = 0; j < 4; j++)
          acc[i][j] = __builtin_amdgcn_mfma_f32_16x16x32_bf16(af[i], bfr[j], acc[i][j], 0, 0, 0);
    }
  }

  const int crow0 = bm * 128 + wr * 64, ccol0 = bn * 128 + wc * 64;
#pragma unroll
  for (int i = 0; i < 4; i++)
#pragma unroll
    for (int j = 0; j < 4; j++) {
      int col = ccol0 + j * 16 + (lane & 15);
#pragma unroll
      for (int r = 0; r < 4; r++) {
        int row = crow0 + i * 16 + (lane >> 4) * 4 + r;
        if (OUTF32)
          ((float*)C)[(size_t)row * N + col] = acc[i][j][r];
        else
          ((__bf16*)C)[(size_t)row * N + col] = (__bf16)acc[i][j][r];
      }
    }
}

// ---------------- V transpose: qkv V-part [b][t][h*64+d] -> vt [b][h][d][t] ----------------
__global__ __launch_bounds__(256) void vtrans(const __bf16* __restrict__ qkv,
                                              __bf16* __restrict__ vt) {
  int tt = blockIdx.x & 31;
  int h = (blockIdx.x >> 5) & 15;
  int b = blockIdx.x >> 9;
  __shared__ __bf16 tile[64 * 64];  // [t][d]
  int tid = threadIdx.x;
  int trow = tid >> 2, c16 = (tid & 3) * 16;
#pragma unroll
  for (int u = 0; u < 2; ++u)
    *(bf16x8*)&tile[trow * 64 + c16 + u * 8] =
        *(const bf16x8*)(qkv + (size_t)(b * TSEQ + tt * 64 + trow) * NQKV + 2 * DM + h * DH + c16 + u * 8);
  __syncthreads();
  int drow = tid >> 2, t16 = (tid & 3) * 16;
  bf16x8 o0, o1;
#pragma unroll
  for (int u = 0; u < 8; u++) o0[u] = tile[(t16 + u) * 64 + drow];
#pragma unroll
  for (int u = 0; u < 8; u++) o1[u] = tile[(t16 + 8 + u) * 64 + drow];
  __bf16* dst = vt + ((size_t)((b * NH + h) * DH) + drow) * TSEQ + tt * 64 + t16;
  *(bf16x8*)dst = o0;
  *(bf16x8*)(dst + 8) = o1;
}

// ---------------- causal flash attention ----------------
// block = (b, h, 64-row q tile); 4 waves x 16 q-rows; KV tiles of 64.
// K LDS [s][d] + Vt LDS [d][s], both XOR-swizzled via pre-swizzled global source.
__global__ __launch_bounds__(256) void attn(const __bf16* __restrict__ qkv,
                                            const __bf16* __restrict__ vt,
                                            __bf16* __restrict__ y) {
  const int qt = blockIdx.x & 31;
  const int h = (blockIdx.x >> 5) & 15;
  const int b = blockIdx.x >> 9;
  const int tid = threadIdx.x, lane = tid & 63, w = tid >> 6;

  __shared__ __bf16 Ks[64 * 64];
  __shared__ __bf16 Vs[64 * 64];
  __shared__ __bf16 Ps[4][16 * 64];

  // Q fragments: rows qt*64 + w*16 + (lane&15)
  const int qrow = qt * 64 + w * 16 + (lane & 15);
  const __bf16* qptr = qkv + (size_t)(b * TSEQ + qrow) * NQKV + h * DH;
  bf16x8 qf[2];
  qf[0] = *(const bf16x8*)(qptr + (lane >> 4) * 8);
  qf[1] = *(const bf16x8*)(qptr + 32 + (lane >> 4) * 8);

  f32x4 o[4];
  float m[4], l[4];
#pragma unroll
  for (int j = 0; j < 4; j++) o[j] = (f32x4){0.f, 0.f, 0.f, 0.f};
#pragma unroll
  for (int r = 0; r < 4; r++) { m[r] = -1e30f; l[r] = 0.f; }

  const int nt = qt + 1;
  const __bf16* kg = qkv + (size_t)b * TSEQ * NQKV + DM + h * DH;
  const __bf16* vg = vt + (size_t)((b * NH + h) * DH) * TSEQ;

  for (int t0 = 0; t0 < nt; ++t0) {
    const int s0 = t0 * 64;
    __syncthreads();
#pragma unroll
    for (int it = 0; it < 2; ++it) {
      int e = it * 256 + tid;
      int row = e >> 3, slot = e & 7;
      int gc = ((slot ^ (row & 7)) * 8);
      gload_lds16(kg + (size_t)(s0 + row) * NQKV + gc, Ks + e * 8);
      gload_lds16(vg + (size_t)row * TSEQ + s0 + gc, Vs + e * 8);
    }
    __syncthreads();

    // S = Q K^T (16x64 per wave)
    f32x4 s[4];
#pragma unroll
    for (int j = 0; j < 4; j++) s[j] = (f32x4){0.f, 0.f, 0.f, 0.f};
#pragma unroll
    for (int kk = 0; kk < 2; kk++) {
      const int c2 = (kk * 32 + (lane >> 4) * 8) * 2;
#pragma unroll
      for (int j = 0; j < 4; j++) {
        int row = j * 16 + (lane & 15);
        bf16x8 kf = *(const bf16x8*)((const char*)Ks + row * 128 + (c2 ^ ((row & 7) << 4)));
        s[j] = __builtin_amdgcn_mfma_f32_16x16x32_bf16(qf[kk], kf, s[j], 0, 0, 0);
      }
    }

    // mask + scale + online softmax (row stats within 16-lane groups)
    float p[4][4];
#pragma unroll
    for (int r = 0; r < 4; r++) {
      const int qg = qt * 64 + w * 16 + (lane >> 4) * 4 + r;
      float rm = -1e30f;
#pragma unroll
      for (int j = 0; j < 4; j++) {
        int sg = s0 + j * 16 + (lane & 15);
        float v = s[j][r] * 0.125f;
        if (sg > qg) v = -1e30f;
        p[j][r] = v;
        rm = fmaxf(rm, v);
      }
#pragma unroll
      for (int mk = 1; mk < 16; mk <<= 1) rm = fmaxf(rm, __shfl_xor(rm, mk));
      float mnew = fmaxf(m[r], rm);
      float alpha = __expf(m[r] - mnew);
      m[r] = mnew;
      l[r] *= alpha;
#pragma unroll
      for (int j = 0; j < 4; j++) {
        float pv = __expf(p[j][r] - mnew);
        p[j][r] = pv;
        l[r] += pv;
      }
#pragma unroll
      for (int j = 0; j < 4; j++) o[j][r] *= alpha;
    }

    // write P (bf16, swizzled) to per-wave LDS
#pragma unroll
    for (int r = 0; r < 4; r++) {
      int prow = (lane >> 4) * 4 + r;
#pragma unroll
      for (int j = 0; j < 4; j++) {
        int scol = j * 16 + (lane & 15);
        *(__bf16*)((char*)Ps[w] + prow * 128 + ((scol * 2) ^ ((prow & 7) << 4))) = (__bf16)p[j][r];
      }
    }
    __syncthreads();

    // O += P V
#pragma unroll
    for (int kk = 0; kk < 2; kk++) {
      const int c2 = (kk * 32 + (lane >> 4) * 8) * 2;
      const int prow = lane & 15;
      bf16x8 pf = *(const bf16x8*)((const char*)Ps[w] + prow * 128 + (c2 ^ ((prow & 7) << 4)));
#pragma unroll
      for (int dj = 0; dj < 4; dj++) {
        int vrow = dj * 16 + (lane & 15);
        bf16x8 vf = *(const bf16x8*)((const char*)Vs + vrow * 128 + (c2 ^ ((vrow & 7) << 4)));
        o[dj] = __builtin_amdgcn_mfma_f32_16x16x32_bf16(pf, vf, o[dj], 0, 0, 0);
      }
    }
  }

  // finalize: divide by row sum, write y[b][t][h*64+d] (bf16)
#pragma unroll
  for (int r = 0; r < 4; r++) {
    float lr = l[r];
#pragma unroll
    for (int mk = 1; mk < 16; mk <<= 1) lr += __shfl_xor(lr, mk);
    l[r] = 1.f / lr;
  }
#pragma unroll
  for (int dj = 0; dj < 4; dj++)
#pragma unroll
    for (int r = 0; r < 4; r++) {
      int row = qt * 64 + w * 16 + (lane >> 4) * 4 + r;
      int col = h * DH + dj * 16 + (lane & 15);
      y[(size_t)(b * TSEQ + row) * DM + col] = (__bf16)(o[dj][r] * l[r]);
    }
}

// ---------------- launcher ----------------
extern "C" void kernel_launch(void* const* d_in, const int* in_sizes, int n_in,
                              void* d_out, int out_size, void* d_ws, size_t ws_size,
                              hipStream_t stream) {
  const float* x = (const float*)d_in[0];
  const float* w_qkv = (const float*)d_in[1];
  const float* w_proj = (const float*)d_in[2];
  float* out = (float*)d_out;

  char* ws = (char*)d_ws;
  __bf16* xb   = (__bf16*)(ws);                          // 16,777,216 B
  __bf16* wqb  = (__bf16*)(ws + 16777216);               //  6,291,456 B
  __bf16* wpb  = (__bf16*)(ws + 23068672);               //  2,097,152 B
  __bf16* qkvb = (__bf16*)(ws + 25165824);               // 50,331,648 B
  __bf16* vtb  = (__bf16*)(ws + 75497472);               // 16,777,216 B
  __bf16* yb   = (__bf16*)(ws + 92274688);               // 16,777,216 B  (total ~109 MB)

  cvt_bf16<<<1024, 256, 0, stream>>>(x, xb, NROW * DM / 8);
  cvt_bf16<<<512, 256, 0, stream>>>(w_qkv, wqb, NQKV * DM / 8);
  cvt_bf16<<<256, 256, 0, stream>>>(w_proj, wpb, DM * DM / 8);

  gemm_bt<0><<<(NROW / 128) * (NQKV / 128), 256, 0, stream>>>(xb, wqb, qkvb, NROW, NQKV, DM);
  vtrans<<<BATCH * NH * (TSEQ / 64), 256, 0, stream>>>(qkvb, vtb);
  attn<<<BATCH * NH * (TSEQ / 64), 256, 0, stream>>>(qkvb, vtb, yb);
  gemm_bt<1><<<(NROW / 128) * (DM / 128), 256, 0, stream>>>(yb, wpb, out, NROW, DM, DM);
}

// Round 5
// 267.077 us; speedup vs baseline: 1.4767x; 1.4767x over previous
//
#include <hip/hip_runtime.h>
#include <hip/hip_bf16.h>
#include <stdint.h>

#define DM   1024
#define NH   16
#define DH   64
#define TSEQ 2048
#define BATCH 4
#define NROW 8192      // B*T
#define NQKV 3072

typedef __attribute__((ext_vector_type(8)))  __bf16 bf16x8;
typedef __attribute__((ext_vector_type(4)))  float  f32x4;
typedef __attribute__((ext_vector_type(16))) float  f32x16;

static __device__ __forceinline__ void gload_lds16(const __bf16* g, __bf16* l) {
  __builtin_amdgcn_global_load_lds((const __attribute__((address_space(1))) void*)g,
                                   (__attribute__((address_space(3))) void*)l, 16, 0, 0);
}
static __device__ __forceinline__ float exp2a(float x) {
  float r; asm("v_exp_f32 %0, %1" : "=v"(r) : "v"(x)); return r;
}
static __device__ __forceinline__ uint32_t cvtpk(float a, float b) {
  uint32_t r; asm("v_cvt_pk_bf16_f32 %0, %1, %2" : "=v"(r) : "v"(a), "v"(b)); return r;
}

// ---------------- fp32 -> bf16 convert, 8 elems/thread ----------------
__global__ __launch_bounds__(256) void cvt_bf16(const float* __restrict__ in,
                                                __bf16* __restrict__ out, int n8) {
  int i = blockIdx.x * blockDim.x + threadIdx.x;
  int stride = gridDim.x * blockDim.x;
  for (; i < n8; i += stride) {
    const float4* p = (const float4*)(in + (size_t)i * 8);
    float4 a = p[0], b = p[1];
    bf16x8 o;
    o[0] = (__bf16)a.x; o[1] = (__bf16)a.y; o[2] = (__bf16)a.z; o[3] = (__bf16)a.w;
    o[4] = (__bf16)b.x; o[5] = (__bf16)b.y; o[6] = (__bf16)b.z; o[7] = (__bf16)b.w;
    *(bf16x8*)(out + (size_t)i * 8) = o;
  }
}

// ---------------- bf16 GEMM, C = A[M,K] * B[N,K]^T (m97 structure) ----------------
template <int OUTF32>
__global__ __launch_bounds__(256) void gemm_bt(const __bf16* __restrict__ A,
                                               const __bf16* __restrict__ B,
                                               void* __restrict__ C,
                                               int M, int N, int K) {
  __shared__ __bf16 As[128 * 64];
  __shared__ __bf16 Bs[128 * 64];
  const int nbn = N >> 7;
  const int bm = blockIdx.x / nbn, bn = blockIdx.x % nbn;
  const int tid = threadIdx.x;
  const int lane = tid & 63, wid = tid >> 6;
  const int wr = wid >> 1, wc = wid & 1;

  f32x4 acc[4][4];
#pragma unroll
  for (int i = 0; i < 4; i++)
#pragma unroll
    for (int j = 0; j < 4; j++) acc[i][j] = (f32x4){0.f, 0.f, 0.f, 0.f};

  const __bf16* Abase = A + (size_t)(bm * 128) * K;
  const __bf16* Bbase = B + (size_t)(bn * 128) * K;

  for (int k0 = 0; k0 < K; k0 += 64) {
    __syncthreads();
#pragma unroll
    for (int it = 0; it < 4; ++it) {
      int e = it * 256 + tid;
      int row = e >> 3, c = (e & 7) * 8;
      gload_lds16(Abase + (size_t)row * K + k0 + c, As + e * 8);
      gload_lds16(Bbase + (size_t)row * K + k0 + c, Bs + e * 8);
    }
    __syncthreads();
#pragma unroll
    for (int kk = 0; kk < 2; ++kk) {
      const int kb = kk * 32 + (lane >> 4) * 8;
      bf16x8 af[4], bfr[4];
#pragma unroll
      for (int i = 0; i < 4; i++)
        af[i] = *(const bf16x8*)&As[(wr * 64 + i * 16 + (lane & 15)) * 64 + kb];
#pragma unroll
      for (int j = 0; j < 4; j++)
        bfr[j] = *(const bf16x8*)&Bs[(wc * 64 + j * 16 + (lane & 15)) * 64 + kb];
#pragma unroll
      for (int i = 0; i < 4; i++)
#pragma unroll
        for (int j = 0; j < 4; j++)
          acc[i][j] = __builtin_amdgcn_mfma_f32_16x16x32_bf16(af[i], bfr[j], acc[i][j], 0, 0, 0);
    }
  }

  const int crow0 = bm * 128 + wr * 64, ccol0 = bn * 128 + wc * 64;
#pragma unroll
  for (int i = 0; i < 4; i++)
#pragma unroll
    for (int j = 0; j < 4; j++) {
      int col = ccol0 + j * 16 + (lane & 15);
#pragma unroll
      for (int r = 0; r < 4; r++) {
        int row = crow0 + i * 16 + (lane >> 4) * 4 + r;
        if (OUTF32)
          ((float*)C)[(size_t)row * N + col] = acc[i][j][r];
        else
          ((__bf16*)C)[(size_t)row * N + col] = (__bf16)acc[i][j][r];
      }
    }
}

// ---------------- V transpose: qkv V-part [b][t][h*64+d] -> vt [b][h][d][t] ----------------
__global__ __launch_bounds__(256) void vtrans(const __bf16* __restrict__ qkv,
                                              __bf16* __restrict__ vt) {
  int tt = blockIdx.x & 31;
  int h = (blockIdx.x >> 5) & 15;
  int b = blockIdx.x >> 9;
  __shared__ __bf16 tile[64 * 64];  // [t][d]
  int tid = threadIdx.x;
  int trow = tid >> 2, c16 = (tid & 3) * 16;
#pragma unroll
  for (int u = 0; u < 2; ++u)
    *(bf16x8*)&tile[trow * 64 + c16 + u * 8] =
        *(const bf16x8*)(qkv + (size_t)(b * TSEQ + tt * 64 + trow) * NQKV + 2 * DM + h * DH + c16 + u * 8);
  __syncthreads();
  int drow = tid >> 2, t16 = (tid & 3) * 16;
  bf16x8 o0, o1;
#pragma unroll
  for (int u = 0; u < 8; u++) o0[u] = tile[(t16 + u) * 64 + drow];
#pragma unroll
  for (int u = 0; u < 8; u++) o1[u] = tile[(t16 + 8 + u) * 64 + drow];
  __bf16* dst = vt + ((size_t)((b * NH + h) * DH) + drow) * TSEQ + tt * 64 + t16;
  *(bf16x8*)dst = o0;
  *(bf16x8*)(dst + 8) = o1;
}

// ---------------- causal flash attention, swapped-QK^T 32x32 in-register softmax ----------------
// grid 1024: qt = 15 - (bid>>6) (heavy-first), bh = bid&63. 4 waves x 32 q-rows = 128 q/block.
// S^T = mfma(K, Q): lane holds S[q=lane&31][kv=crow(r,hi)]. Softmax in-register (T12), defer-max (T13).
// KEY: A-frag fine structure is interleaved (k = 8*(e>>2) + 4*hi + (e&3)), so the QK^T C/D output
// IS the PV A-operand after pairwise bf16 packing (element e == sacc reg e) — no cross-lane moves.
// The V B-operand read must match the same interleave: two 8-byte chunks {4hi..+3} and {8+4hi..+3}.
__global__ __launch_bounds__(256, 4) void attn2(const __bf16* __restrict__ qkv,
                                                const __bf16* __restrict__ vt,
                                                __bf16* __restrict__ y) {
  const int bid = blockIdx.x;
  const int qt = 15 - (bid >> 6);
  const int bh = bid & 63;
  const int b = bh >> 4, h = bh & 15;
  const int tid = threadIdx.x, lane = tid & 63, w = tid >> 6;
  const int lq = lane & 31, hi = lane >> 5;
  const int qb0 = qt * 128 + w * 32;
  const float C2 = 0.125f * 1.44269504f;  // scale * log2(e); logits in log2 domain

  __shared__ __bf16 Ks[64 * 64];  // [s][d], XOR-swizzled
  __shared__ __bf16 Vs[64 * 64];  // [d][s], XOR-swizzled

  // Q as B-operand fragments (joint-permutation with K A-frags -> contiguous load OK)
  const __bf16* qp = qkv + (size_t)(b * TSEQ + qb0 + lq) * NQKV + h * DH;
  bf16x8 qf[4];
#pragma unroll
  for (int ks = 0; ks < 4; ks++) qf[ks] = *(const bf16x8*)(qp + ks * 16 + hi * 8);

  f32x16 o0 = {}, o1 = {};           // O d-halves; row=crow(r,hi)=q, col=lq=d
  float m = -1e30f, lsum = 0.f;      // stats for q-row lq (lane pair l, l+32 agree)

  const __bf16* kg = qkv + (size_t)b * TSEQ * NQKV + DM + h * DH;
  const __bf16* vg = vt + (size_t)((b * NH + h) * DH) * TSEQ;

  const int nkv = (qt + 1) * 2;
  for (int t0 = 0; t0 < nkv; ++t0) {
    const int s0 = t0 * 64;
    __syncthreads();
#pragma unroll
    for (int it = 0; it < 2; ++it) {  // stage K [64][64] + V [64][64]
      int e = it * 256 + tid;
      int row = e >> 3, slot = e & 7;
      int gc = (slot ^ (row & 7)) * 8;
      gload_lds16(kg + (size_t)(s0 + row) * NQKV + gc, Ks + e * 8);
      gload_lds16(vg + (size_t)row * TSEQ + s0 + gc, Vs + e * 8);
    }
    __syncthreads();

    if (s0 > qb0 + 31) continue;  // wave-uniform: fully beyond this wave's diagonal

#pragma unroll
    for (int g = 0; g < 2; ++g) {
      const int s0g = s0 + g * 32;
      if (s0g <= qb0 + 31) {
        // ---- S^T = K·Q^T over D=64 (4 k-steps) ----
        f32x16 sacc = {};
#pragma unroll
        for (int ks = 0; ks < 4; ks++) {
          int row = g * 32 + lq;
          int cb = (ks * 32 + hi * 16) ^ ((row & 7) << 4);
          bf16x8 kf = *(const bf16x8*)((const char*)Ks + row * 128 + cb);
          sacc = __builtin_amdgcn_mfma_f32_32x32x16_bf16(kf, qf[ks], sacc, 0, 0, 0);
        }
        // ---- scale + causal mask (reg r -> kv = s0g + (r&3)+8*(r>>2)+4*hi, q=lq) ----
        const int qg = qb0 + lq;
        const int kvb = s0g + (hi << 2);
        if (s0g + 31 > qb0) {
#pragma unroll
          for (int r = 0; r < 16; r++) {
            const int off = (r & 3) + 8 * (r >> 2);
            sacc[r] = (kvb + off > qg) ? -3.0e38f : sacc[r] * C2;
          }
        } else {
#pragma unroll
          for (int r = 0; r < 16; r++) sacc[r] *= C2;
        }
        // ---- row max: in-reg tree + pair exchange ----
        float pm = -3.0e38f;
#pragma unroll
        for (int r = 0; r < 16; r++) pm = fmaxf(pm, sacc[r]);
        pm = fmaxf(pm, __shfl_xor(pm, 32));
        // ---- defer-max (T13): rescale only if some row grew > 8 (log2) ----
        if (__any(pm > m + 8.0f)) {
          float mn = fmaxf(m, pm);
          float al = exp2a(m - mn);
          m = mn;
          lsum *= al;
#pragma unroll
          for (int r = 0; r < 16; r++) {
            const int off = (r & 3) + 8 * (r >> 2);
            float ar = __shfl(al, off + (hi << 2), 64);
            o0[r] *= ar; o1[r] *= ar;
          }
        }
        // ---- P = exp2(S - m); pack pairwise: A-frag element e == sacc reg e (identity) ----
        union { uint32_t u[4]; bf16x8 v; } pa0, pa1;
        {
          float pe[16];
#pragma unroll
          for (int r = 0; r < 16; r++) { pe[r] = exp2a(sacc[r] - m); lsum += pe[r]; }
#pragma unroll
          for (int i = 0; i < 4; i++) pa0.u[i] = cvtpk(pe[2 * i], pe[2 * i + 1]);
#pragma unroll
          for (int i = 0; i < 4; i++) pa1.u[i] = cvtpk(pe[8 + 2 * i], pe[9 + 2 * i]);
        }
        // ---- O += P·V; V B-frag interleaved: s-offsets {4hi..+3} and {8+4hi..+3} ----
#pragma unroll
        for (int ks2 = 0; ks2 < 2; ks2++) {
          const bf16x8 pa = ks2 ? pa1.v : pa0.v;
#pragma unroll
          for (int dh = 0; dh < 2; dh++) {
            int row = dh * 32 + lq;
            int sw = (row & 7) << 4;
            int b0 = g * 64 + ks2 * 32 + hi * 8;  // byte offset of sub-chunk {4hi..4hi+3}
            const char* base = (const char*)Vs + row * 128;
            union { uint32_t u[4]; bf16x8 v; } vf;
            *(uint2*)&vf.u[0] = *(const uint2*)(base + (b0 ^ sw));
            *(uint2*)&vf.u[2] = *(const uint2*)(base + ((b0 + 16) ^ sw));
            if (dh == 0) o0 = __builtin_amdgcn_mfma_f32_32x32x16_bf16(pa, vf.v, o0, 0, 0, 0);
            else         o1 = __builtin_amdgcn_mfma_f32_32x32x16_bf16(pa, vf.v, o1, 0, 0, 0);
          }
        }
      }
    }
  }

  // ---- finalize: L = pair-sum, broadcast 1/L to O layout, store ----
  float Lf = lsum + __shfl_xor(lsum, 32);
  float inv = 1.0f / Lf;
#pragma unroll
  for (int r = 0; r < 16; r++) {
    const int off = (r & 3) + 8 * (r >> 2);
    float ivr = __shfl(inv, off + (hi << 2), 64);
    int qrow = qb0 + off + (hi << 2);
    __bf16* yp = y + (size_t)(b * TSEQ + qrow) * DM + h * DH;
    yp[lq] = (__bf16)(o0[r] * ivr);
    yp[32 + lq] = (__bf16)(o1[r] * ivr);
  }
}

// ---------------- launcher ----------------
extern "C" void kernel_launch(void* const* d_in, const int* in_sizes, int n_in,
                              void* d_out, int out_size, void* d_ws, size_t ws_size,
                              hipStream_t stream) {
  const float* x = (const float*)d_in[0];
  const float* w_qkv = (const float*)d_in[1];
  const float* w_proj = (const float*)d_in[2];
  float* out = (float*)d_out;

  char* ws = (char*)d_ws;
  __bf16* xb   = (__bf16*)(ws);
  __bf16* wqb  = (__bf16*)(ws + 16777216);
  __bf16* wpb  = (__bf16*)(ws + 23068672);
  __bf16* qkvb = (__bf16*)(ws + 25165824);
  __bf16* vtb  = (__bf16*)(ws + 75497472);
  __bf16* yb   = (__bf16*)(ws + 92274688);

  cvt_bf16<<<1024, 256, 0, stream>>>(x, xb, NROW * DM / 8);
  cvt_bf16<<<512, 256, 0, stream>>>(w_qkv, wqb, NQKV * DM / 8);
  cvt_bf16<<<256, 256, 0, stream>>>(w_proj, wpb, DM * DM / 8);

  gemm_bt<0><<<(NROW / 128) * (NQKV / 128), 256, 0, stream>>>(xb, wqb, qkvb, NROW, NQKV, DM);
  vtrans<<<BATCH * NH * (TSEQ / 64), 256, 0, stream>>>(qkvb, vtb);
  attn2<<<BATCH * NH * (TSEQ / 128), 256, 0, stream>>>(qkvb, vtb, yb);
  gemm_bt<1><<<(NROW / 128) * (DM / 128), 256, 0, stream>>>(yb, wpb, out, NROW, DM, DM);
}